// Round 14
// baseline (1129.625 us; speedup 1.0000x reference)
//
#include <hip/hip_runtime.h>
#include <stdint.h>

#define NBN   25088   // 128 * 196  (TB * N)
#define NTOK  196
#define BATCH 32
#define CDIM  384
#define HDIM  1536
#define NHEAD 12

typedef float f32x4 __attribute__((ext_vector_type(4)));

#define GLDS16(g, l) __builtin_amdgcn_global_load_lds( \
    (const __attribute__((address_space(1))) void*)(g), \
    (__attribute__((address_space(3))) void*)(l), 16, 0, 0)

// ---------------- transpose: x (TB,C,N) -> xT (C, TB*N) ------------------------
__global__ __launch_bounds__(256) void k_transpose(const float* __restrict__ x,
                                                   float* __restrict__ xT) {
  int id = blockIdx.x * 256 + threadIdx.x;
  int c = id / NBN;
  int r = id - c * NBN;
  int b = r / NTOK;
  int n = r - b * NTOK;
  xT[id] = x[((size_t)b * CDIM + c) * NTOK + n];
}

// ---- weight transpose: src (R,C) -> dst[c*ldd + coff + r], grid (C/32, R/32) --
__global__ __launch_bounds__(256) void k_wT(const float* __restrict__ src,
                                            float* __restrict__ dst,
                                            int C, int ldd, int coff) {
  __shared__ float t[32][33];
  const int c0 = blockIdx.x * 32, r0 = blockIdx.y * 32;
  const int tx = threadIdx.x & 31, ty = threadIdx.x >> 5;   // 32 x 8
#pragma unroll
  for (int i = 0; i < 4; ++i)
    t[ty + i * 8][tx] = src[(size_t)(r0 + ty + i * 8) * C + c0 + tx];
  __syncthreads();
#pragma unroll
  for (int i = 0; i < 4; ++i)
    dst[(size_t)(c0 + ty + i * 8) * ldd + coff + r0 + tx] = t[tx][ty + i * 8];
}

// ---------------------------------------------------------------------------
// fp32 float-B GEMM v14, chain-exact (k-ascending fmaf per output).
// 128x256 tile, 8x16 microtile (acc[8][16]): per kk only 6 ds_read_b128 feed
// 128 FMAs (vs 4:64 before) -> LDS-issue ceiling 0.67 -> 0.89.
// B cols per thread split as c*4 + q*64 (bank-quad 2-way = free).
// glds staging, one vmcnt(0)+barrier per K-tile (r10-proven schedule).
// ---------------------------------------------------------------------------
__global__ __launch_bounds__(256, 2) void k_gemmf(
    const float* __restrict__ WT, const float* __restrict__ X,
    const float* __restrict__ bias, float* __restrict__ Y,
    double* __restrict__ pS, double* __restrict__ pS2, int K, int Mtot) {
  __shared__ float As[32][128];
  __shared__ float Bs[32][256];
  const int tid = threadIdx.x;
  const int lane = tid & 63, wv = tid >> 6;
  const int gy = blockIdx.x, bn = blockIdx.y;   // gy fast: B-tile sharing
  const int wcol = gy * 128;
  const int r = tid >> 4, c = tid & 15;
  const int NK = K >> 5;
  const int lrowA = wv * 2 + (lane >> 5), lcolA = (lane & 31) * 4;

  float acc[8][16];
#pragma unroll
  for (int i = 0; i < 8; ++i)
#pragma unroll
    for (int j = 0; j < 16; ++j) acc[i][j] = 0.f;

  for (int ks = 0; ks < NK; ++ks) {
    const int k0 = ks << 5;
    __syncthreads();
    // ---- stage A (32 x 128): 4 glds/wave, 2 rows each ----
#pragma unroll
    for (int i = 0; i < 4; ++i)
      GLDS16(WT + (size_t)(k0 + i * 8 + lrowA) * Mtot + wcol + lcolA,
             &As[i * 8 + wv * 2][0]);
    // ---- stage B (32 x 256): 8 glds/wave, 1 row each ----
#pragma unroll
    for (int i = 0; i < 8; ++i)
      GLDS16(X + (size_t)(k0 + wv * 8 + i) * NBN + bn * 256 + lane * 4,
             &Bs[wv * 8 + i][0]);
    asm volatile("s_waitcnt vmcnt(0)" ::: "memory");
    __syncthreads();

    // ---- compute: k-ascending fused-FMA chain per output ----
#pragma unroll
    for (int kk = 0; kk < 32; ++kk) {
      f32x4 a0 = *reinterpret_cast<const f32x4*>(&As[kk][r * 8]);
      f32x4 a1 = *reinterpret_cast<const f32x4*>(&As[kk][r * 8 + 4]);
      f32x4 b0 = *reinterpret_cast<const f32x4*>(&Bs[kk][c * 4]);
      f32x4 b1 = *reinterpret_cast<const f32x4*>(&Bs[kk][64 + c * 4]);
      f32x4 b2 = *reinterpret_cast<const f32x4*>(&Bs[kk][128 + c * 4]);
      f32x4 b3 = *reinterpret_cast<const f32x4*>(&Bs[kk][192 + c * 4]);
#pragma unroll
      for (int i = 0; i < 8; ++i) {
        const float av = (i < 4) ? a0[i] : a1[i - 4];
#pragma unroll
        for (int j = 0; j < 4; ++j) {
          acc[i][j]      = fmaf(av, b0[j], acc[i][j]);
          acc[i][4 + j]  = fmaf(av, b1[j], acc[i][4 + j]);
          acc[i][8 + j]  = fmaf(av, b2[j], acc[i][8 + j]);
          acc[i][12 + j] = fmaf(av, b3[j], acc[i][12 + j]);
        }
      }
    }
  }

  // ---- epilogue: bias, store, f64 BN partials ----
#pragma unroll
  for (int i = 0; i < 8; ++i) {
    const int row = wcol + r * 8 + i;
    const float bv = bias ? bias[row] : 0.f;
    double s = 0.0, s2 = 0.0;
#pragma unroll
    for (int q = 0; q < 4; ++q) {
      float4 o;
      o.x = acc[i][q * 4 + 0] + bv;
      o.y = acc[i][q * 4 + 1] + bv;
      o.z = acc[i][q * 4 + 2] + bv;
      o.w = acc[i][q * 4 + 3] + bv;
      *reinterpret_cast<float4*>(&Y[(size_t)row * NBN + bn * 256 + q * 64 + c * 4]) = o;
      s += (double)o.x + (double)o.y + (double)o.z + (double)o.w;
      s2 += (double)o.x * o.x + (double)o.y * o.y + (double)o.z * o.z +
            (double)o.w * o.w;
    }
#pragma unroll
    for (int off = 1; off < 16; off <<= 1) {
      s += __shfl_xor(s, off, 64);
      s2 += __shfl_xor(s2, off, 64);
    }
    if (c == 0) {
      pS[(size_t)bn * Mtot + row] = s;
      pS2[(size_t)bn * Mtot + row] = s2;
    }
  }
}

// ---------------------------------------------------------------------------
// u8-B GEMM (round-10-proven, MT=64): BK=32, glds A staging, reg B expand.
// ---------------------------------------------------------------------------
__global__ __launch_bounds__(256, 3) void k_gemmu8(
    const float* __restrict__ WT, const uint8_t* __restrict__ X,
    const float* __restrict__ bias, float* __restrict__ Y,
    double* __restrict__ pS, double* __restrict__ pS2, int K, int Mtot) {
  __shared__ float As[32][64];
  __shared__ float Bs[32][128];
  const int tid = threadIdx.x;
  const int lane = tid & 63, wv = tid >> 6;
  const int gy = blockIdx.x, bn = blockIdx.y;
  const int wcol = gy * 64;
  const int tx = tid & 15, ty = tid >> 4;
  const int NK = K >> 5;

  float acc[4][8];
#pragma unroll
  for (int i = 0; i < 4; ++i)
#pragma unroll
    for (int j = 0; j < 8; ++j) acc[i][j] = 0.f;

  for (int ks = 0; ks < NK; ++ks) {
    const int k0 = ks << 5;
    __syncthreads();
    {
      const int lrow = wv * 4 + (lane >> 4), lcol = (lane & 15) * 4;
#pragma unroll
      for (int i = 0; i < 2; ++i)
        GLDS16(WT + (size_t)(k0 + i * 16 + lrow) * Mtot + wcol + lcol,
               &As[i * 16 + wv * 4][0]);
    }
    {
      const int rr = tid >> 3, c16 = tid & 7;
      const uint4 d = *reinterpret_cast<const uint4*>(
          &X[(size_t)(k0 + rr) * NBN + bn * 128 + c16 * 16]);
      const uint32_t wd[4] = {d.x, d.y, d.z, d.w};
#pragma unroll
      for (int q = 0; q < 4; ++q) {
        f32x4 f;
        f[0] = (float)(wd[q] & 0xffu);
        f[1] = (float)((wd[q] >> 8) & 0xffu);
        f[2] = (float)((wd[q] >> 16) & 0xffu);
        f[3] = (float)(wd[q] >> 24);
        *reinterpret_cast<f32x4*>(&Bs[rr][c16 * 16 + q * 4]) = f;
      }
    }
    asm volatile("s_waitcnt vmcnt(0)" ::: "memory");
    __syncthreads();

    auto lA0 = [&](int kk) { return *reinterpret_cast<const f32x4*>(&As[kk][ty * 4]); };
    auto lB0 = [&](int kk) { return *reinterpret_cast<const f32x4*>(&Bs[kk][tx * 4]); };
    auto lB1 = [&](int kk) { return *reinterpret_cast<const f32x4*>(&Bs[kk][64 + tx * 4]); };
    auto FMA = [&](f32x4 a0, f32x4 b0, f32x4 b1) {
#pragma unroll
      for (int i = 0; i < 4; ++i)
#pragma unroll
        for (int j = 0; j < 8; ++j) {
          const float bv = (j < 4) ? b0[j] : b1[j - 4];
          acc[i][j] = fmaf(a0[i], bv, acc[i][j]);
        }
    };
    f32x4 xa0, xb0, xb1, ya0, yb0, yb1;
    xa0 = lA0(0);
    xb0 = lB0(0);
    xb1 = lB1(0);
#pragma unroll
    for (int kk = 0; kk < 32; kk += 2) {
      ya0 = lA0(kk + 1);
      yb0 = lB0(kk + 1);
      yb1 = lB1(kk + 1);
      FMA(xa0, xb0, xb1);
      if (kk + 2 < 32) {
        xa0 = lA0(kk + 2);
        xb0 = lB0(kk + 2);
        xb1 = lB1(kk + 2);
      }
      FMA(ya0, yb0, yb1);
    }
  }

#pragma unroll
  for (int i = 0; i < 4; ++i) {
    const int row = wcol + ty * 4 + i;
    const float bv = bias ? bias[row] : 0.f;
    float4 o0, o1;
    o0.x = acc[i][0] + bv; o0.y = acc[i][1] + bv;
    o0.z = acc[i][2] + bv; o0.w = acc[i][3] + bv;
    o1.x = acc[i][4] + bv; o1.y = acc[i][5] + bv;
    o1.z = acc[i][6] + bv; o1.w = acc[i][7] + bv;
    *reinterpret_cast<float4*>(&Y[(size_t)row * NBN + bn * 128 + tx * 4]) = o0;
    *reinterpret_cast<float4*>(&Y[(size_t)row * NBN + bn * 128 + 64 + tx * 4]) = o1;
    double s = (double)o0.x + (double)o0.y + (double)o0.z + (double)o0.w +
               (double)o1.x + (double)o1.y + (double)o1.z + (double)o1.w;
    double s2 = (double)o0.x * o0.x + (double)o0.y * o0.y + (double)o0.z * o0.z +
                (double)o0.w * o0.w + (double)o1.x * o1.x + (double)o1.y * o1.y +
                (double)o1.z * o1.z + (double)o1.w * o1.w;
#pragma unroll
    for (int off = 1; off < 16; off <<= 1) {
      s += __shfl_xor(s, off, 64);
      s2 += __shfl_xor(s2, off, 64);
    }
    if (tx == 0) {
      pS[(size_t)bn * Mtot + row] = s;
      pS2[(size_t)bn * Mtot + row] = s2;
    }
  }
}

// ---- repack: h1sp u8 (1536, NBN) -> bitsT (NBN, 48 u32) --------------------
__global__ __launch_bounds__(256) void k_repack(const uint8_t* __restrict__ sp,
                                                uint32_t* __restrict__ bitsT) {
  __shared__ uint32_t bb[64][48];
  const int col0 = blockIdx.x * 64;
  const int c = threadIdx.x & 63, q = threadIdx.x >> 6;
#pragma unroll
  for (int wi = 0; wi < 12; ++wi) {
    const int w = q * 12 + wi;
    uint32_t word = 0;
#pragma unroll
    for (int j = 0; j < 32; ++j)
      word |= (uint32_t)(sp[(size_t)(32 * w + j) * NBN + col0 + c] & 1) << j;
    bb[c][w] = word;
  }
  __syncthreads();
  for (int i = threadIdx.x; i < 64 * 48; i += 256)
    bitsT[(size_t)col0 * 48 + i] = bb[i / 48][i % 48];
}

// ---- sparse-exact GEMM for fc2: y[row][c] = bias + sum_{k: s=1} wT[k][row] --
__global__ __launch_bounds__(256) void k_spgemm(
    const uint32_t* __restrict__ bitsT, const float* __restrict__ WT,
    const float* __restrict__ bias, float* __restrict__ Y,
    double* __restrict__ pS, double* __restrict__ pS2) {
  __shared__ float ytile[4][384];
  const int tid = threadIdx.x;
  const int lane = tid & 63, wv = tid >> 6;
  const int c = blockIdx.x * 4 + wv;
  const uint32_t* wb = bitsT + (size_t)c * 48;

  float a0 = 0.f, a1 = 0.f, a2 = 0.f, a3 = 0.f, a4 = 0.f, a5 = 0.f;
  for (int w = 0; w < 48; ++w) {
    uint32_t word = wb[w];
    while (word) {
      const int k = w * 32 + __builtin_ctz(word);
      word &= word - 1;
      const float* wr = WT + (size_t)k * 384;
      a0 += wr[lane];
      a1 += wr[64 + lane];
      a2 += wr[128 + lane];
      a3 += wr[192 + lane];
      a4 += wr[256 + lane];
      a5 += wr[320 + lane];
    }
  }
  ytile[wv][lane]       = a0 + bias[lane];
  ytile[wv][64 + lane]  = a1 + bias[64 + lane];
  ytile[wv][128 + lane] = a2 + bias[128 + lane];
  ytile[wv][192 + lane] = a3 + bias[192 + lane];
  ytile[wv][256 + lane] = a4 + bias[256 + lane];
  ytile[wv][320 + lane] = a5 + bias[320 + lane];
  __syncthreads();
  const int c0 = blockIdx.x * 4;
  for (int r = tid; r < 384; r += 256) {
    float4 v;
    v.x = ytile[0][r]; v.y = ytile[1][r]; v.z = ytile[2][r]; v.w = ytile[3][r];
    *reinterpret_cast<float4*>(&Y[(size_t)r * NBN + c0]) = v;
    double s = (double)v.x + (double)v.y + (double)v.z + (double)v.w;
    double s2 = (double)v.x * v.x + (double)v.y * v.y + (double)v.z * v.z +
                (double)v.w * v.w;
    pS[(size_t)blockIdx.x * 384 + r] = s;
    pS2[(size_t)blockIdx.x * 384 + r] = s2;
  }
}

// ---- BN stat reduce: NP f64 partials per channel ---------------------------
__global__ __launch_bounds__(64) void k_bn_reduceN(const double* __restrict__ pS,
                                                   const double* __restrict__ pS2,
                                                   float* __restrict__ mean,
                                                   float* __restrict__ rstd,
                                                   int Mtot, int NP) {
  const int ch = blockIdx.x, lane = threadIdx.x;
  double s = 0.0, s2 = 0.0;
  for (int j = lane; j < NP; j += 64) {
    s += pS[(size_t)j * Mtot + ch];
    s2 += pS2[(size_t)j * Mtot + ch];
  }
#pragma unroll
  for (int off = 32; off; off >>= 1) {
    s += __shfl_down(s, off, 64);
    s2 += __shfl_down(s2, off, 64);
  }
  if (lane == 0) {
    double m = s / (double)NBN;
    double v = s2 / (double)NBN - m * m;
    mean[ch] = (float)m;
    rstd[ch] = (float)(1.0 / sqrt(v + 1e-5));
  }
}

// ---- BN apply + LIF (thr 1.0) writing PACKED spikes (qkv -> attention) -----
__global__ __launch_bounds__(256) void k_lif_pack(const float* __restrict__ Y,
    const float* __restrict__ mean, const float* __restrict__ rstd,
    const float* __restrict__ g0, const float* __restrict__ g1,
    const float* __restrict__ g2, const float* __restrict__ b0,
    const float* __restrict__ b1, const float* __restrict__ b2,
    uint32_t* __restrict__ pk) {
  const int o = blockIdx.x;
  const int b = threadIdx.x >> 3, w = threadIdx.x & 7;
  int br = o / 384, ol = o - br * 384;
  const float g = (br == 0 ? g0 : br == 1 ? g1 : g2)[ol];
  const float be = (br == 0 ? b0 : br == 1 ? b1 : b2)[ol];
  const float m_ = mean[o], rs_ = rstd[o];
  float mem[32];
#pragma unroll
  for (int j = 0; j < 32; ++j) mem[j] = 0.f;
  for (int t = 0; t < 4; ++t) {
    uint32_t word = 0;
    const size_t base = (size_t)o * NBN + (size_t)(t * 32 + b) * NTOK + w * 32;
#pragma unroll
    for (int q = 0; q < 8; ++q) {
      if (w * 32 + q * 4 < NTOK) {
        float4 v4 = *reinterpret_cast<const float4*>(&Y[base + q * 4]);
        float vv[4] = {v4.x, v4.y, v4.z, v4.w};
#pragma unroll
        for (int jj = 0; jj < 4; ++jj) {
          int j = q * 4 + jj;
          float v = ((vv[jj] - m_) * rs_) * g + be;
          float mm = mem[j];
          mm = mm + (v - mm) * 0.5f;
          bool fire = (mm >= 1.0f);
          mem[j] = fire ? 0.f : mm;
          word |= (fire ? 1u : 0u) << j;
        }
      }
    }
    pk[((size_t)o * 128 + t * 32 + b) * 8 + w] = word;
  }
}

// ---- BN apply + LIF (thr 1.0) writing u8 spikes (fc1 -> fc2 B) -------------
__global__ __launch_bounds__(256) void k_lif_u8(const float* __restrict__ Y,
    const float* __restrict__ mean, const float* __restrict__ rstd,
    const float* __restrict__ gamma, const float* __restrict__ beta,
    uint8_t* __restrict__ sp) {
  const int o = blockIdx.x;
  const int b = threadIdx.x >> 3, w = threadIdx.x & 7;
  const float m_ = mean[o], rs_ = rstd[o], g = gamma[o], be = beta[o];
  float mem[32];
#pragma unroll
  for (int j = 0; j < 32; ++j) mem[j] = 0.f;
  for (int t = 0; t < 4; ++t) {
    const size_t base = (size_t)o * NBN + (size_t)(t * 32 + b) * NTOK + w * 32;
    uint32_t words[8];
#pragma unroll
    for (int q = 0; q < 8; ++q) {
      words[q] = 0;
      if (w * 32 + q * 4 < NTOK) {
        float4 v4 = *reinterpret_cast<const float4*>(&Y[base + q * 4]);
        float vv[4] = {v4.x, v4.y, v4.z, v4.w};
#pragma unroll
        for (int jj = 0; jj < 4; ++jj) {
          int j = q * 4 + jj;
          float v = ((vv[jj] - m_) * rs_) * g + be;
          float mm = mem[j];
          mm = mm + (v - mm) * 0.5f;
          bool fire = (mm >= 1.0f);
          mem[j] = fire ? 0.f : mm;
          words[q] |= (fire ? 1u : 0u) << (8 * jj);
        }
      }
    }
    uint32_t* dst = reinterpret_cast<uint32_t*>(const_cast<uint8_t*>(sp) + base);
#pragma unroll
    for (int q = 0; q < 8; ++q)
      if (w * 32 + q * 4 < NTOK) dst[q] = words[q];
  }
}

// ---- BN apply + LIF, float outputs -----------------------------------------
template <int MODE>
__global__ __launch_bounds__(256) void k_bn_lif(const float* __restrict__ Y,
                                                const float* __restrict__ mean,
                                                const float* __restrict__ rstd,
                                                const float* __restrict__ gamma,
                                                const float* __restrict__ beta,
                                                const float* __restrict__ addsrc,
                                                float* __restrict__ extra) {
  int id = blockIdx.x * 256 + threadIdx.x;
  int o = id / (BATCH * NTOK);
  int r = id - o * (BATCH * NTOK);
  float m_ = mean[o], rs_ = rstd[o], g = gamma[o], be = beta[o];
  float mem = 0.f;
#pragma unroll
  for (int t = 0; t < 4; ++t) {
    size_t idx = (size_t)o * NBN + (size_t)t * (BATCH * NTOK) + r;
    float v = Y[idx];
    v = ((v - m_) * rs_) * g + be;
    mem = mem + (v - mem) * 0.5f;
    bool fire = (mem >= 1.0f);
    float s = fire ? 1.f : 0.f;
    mem = fire ? 0.f : mem;
    if constexpr (MODE == 1) {
      extra[idx] = addsrc[idx] + s;
    } else {
      int b = r / NTOK, n = r - b * NTOK;
      extra[((size_t)(t * BATCH + b) * CDIM + o) * NTOK + n] = addsrc[idx] + s;
    }
  }
}

// ---- attention via popcount (exact integers), u8 output --------------------
__global__ __launch_bounds__(256) void k_attn_pop(const uint32_t* __restrict__ pQ,
                                                  const uint32_t* __restrict__ pK,
                                                  const uint32_t* __restrict__ pV,
                                                  uint8_t* __restrict__ spA) {
  __shared__ __align__(16) uint32_t qw[32][8], kw[32][8], vw[32][8];
  __shared__ int kv[32][33];
  __shared__ uint32_t kvb[8][32];
  __shared__ uint32_t qT[NTOK];
  const int bh = blockIdx.x;
  const int b_ = bh / NHEAD, h = bh - b_ * NHEAD;
  const int tid = threadIdx.x;
  const int e = tid >> 3, w = tid & 7;
  float mem[32];
#pragma unroll
  for (int j = 0; j < 32; ++j) mem[j] = 0.f;

  for (int t = 0; t < 4; ++t) {
    const int tb = t * 32 + b_;
    {
      int d = tid >> 3, wo = tid & 7;
      size_t base = ((size_t)(h * 32 + d) * 128 + tb) * 8 + wo;
      qw[d][wo] = pQ[base];
      kw[d][wo] = pK[base];
      vw[d][wo] = pV[base];
    }
    __syncthreads();
    for (int i = tid; i < 1024; i += 256) {
      int d = i >> 5, ee = i & 31;
      const uint64_t* kp = reinterpret_cast<const uint64_t*>(&kw[d][0]);
      const uint64_t* vp = reinterpret_cast<const uint64_t*>(&vw[ee][0]);
      int s = 0;
#pragma unroll
      for (int u = 0; u < 4; ++u) s += __popcll(kp[u] & vp[u]);
      kv[d][ee] = s;
    }
    __syncthreads();
    {
      int bitb = tid >> 5, ee = tid & 31;
      uint32_t mword = 0;
#pragma unroll
      for (int d = 0; d < 32; ++d) mword |= (uint32_t)((kv[d][ee] >> bitb) & 1) << d;
      kvb[bitb][ee] = mword;
    }
    if (tid < NTOK) {
      uint32_t mword = 0;
#pragma unroll
      for (int d = 0; d < 32; ++d)
        mword |= ((qw[d][tid >> 5] >> (tid & 31)) & 1u) << d;
      qT[tid] = mword;
    }
    __syncthreads();
    uint32_t word = 0;
#pragma unroll
    for (int j = 0; j < 32; ++j) {
      int n = w * 32 + j;
      if (n < NTOK) {
        uint32_t qm = qT[n];
        int acc = 0;
#pragma unroll
        for (int bb = 0; bb < 8; ++bb) acc += __popc(qm & kvb[bb][e]) << bb;
        float val = (float)acc * 0.125f;
        float mm = mem[j];
        mm = mm + (val - mm) * 0.5f;
        bool fire = (mm >= 0.5f);
        mem[j] = fire ? 0.f : mm;
        word |= (fire ? 1u : 0u) << j;
      }
    }
    uint8_t* dst = spA + (size_t)(h * 32 + e) * NBN + (size_t)tb * NTOK + w * 32;
#pragma unroll
    for (int q = 0; q < 8; ++q) {
      if (w * 32 + q * 4 < NTOK) {
        uint32_t b4 = ((word >> (q * 4)) & 1u) | (((word >> (q * 4 + 1)) & 1u) << 8) |
                      (((word >> (q * 4 + 2)) & 1u) << 16) |
                      (((word >> (q * 4 + 3)) & 1u) << 24);
        *reinterpret_cast<uint32_t*>(dst + q * 4) = b4;
      }
    }
    __syncthreads();
  }
}

// ---------------------------------------------------------------------------
extern "C" void kernel_launch(void* const* d_in, const int* in_sizes, int n_in,
                              void* d_out, int out_size, void* d_ws, size_t ws_size,
                              hipStream_t stream) {
  const float* x          = (const float*)d_in[0];
  const float* q_w        = (const float*)d_in[1];
  const float* q_gamma    = (const float*)d_in[2];
  const float* q_beta     = (const float*)d_in[3];
  const float* k_w        = (const float*)d_in[4];
  const float* k_gamma    = (const float*)d_in[5];
  const float* k_beta     = (const float*)d_in[6];
  const float* v_w        = (const float*)d_in[7];
  const float* v_gamma    = (const float*)d_in[8];
  const float* v_beta     = (const float*)d_in[9];
  const float* proj_w     = (const float*)d_in[10];
  const float* proj_b     = (const float*)d_in[11];
  const float* proj_gamma = (const float*)d_in[12];
  const float* proj_beta  = (const float*)d_in[13];
  const float* fc1_w      = (const float*)d_in[14];
  const float* fc1_b      = (const float*)d_in[15];
  const float* bn1_gamma  = (const float*)d_in[16];
  const float* bn1_beta   = (const float*)d_in[17];
  const float* fc2_w      = (const float*)d_in[18];
  const float* fc2_b      = (const float*)d_in[19];
  const float* bn2_gamma  = (const float*)d_in[20];
  const float* bn2_beta   = (const float*)d_in[21];
  float* out = (float*)d_out;
  char* ws = (char*)d_ws;

  // ---- arena (bytes); peak 231,223,296 = round-1-proven footprint --------
  const size_t O_XT   = 0;           // xT f32 (384,NBN) [1..proj-lif]
  const size_t O_YQ   = 38535168;    // yQKV (1152,NBN) / yB
  const size_t O_XRES = 154140672;   // xres (384,NBN) [proj-lif..end]
  const size_t O_PK   = 192675840;   // packed qkv bits 4,718,592
  const size_t O_SPA  = 197394432;   // attn u8 spikes 9,633,792
  const size_t O_H1SP = 192675840;   // u8 (1536,NBN) [fc1-lif..repack]
  const size_t O_H1   = 0;           // fc1 out f32 (1536,NBN)
  const size_t O_ST   = 231211008;   // mean/rstd
  // transient:
  const size_t O_P1   = 154140672;   // qkv/proj partials (consumed pre-xres)
  const size_t O_P1B  = O_P1 + 1806336;
  const size_t O_QKVT = 197394432;   // qkvT 1,769,472 [pre-attn]
  const size_t O_PRJT = 192675840;   // projT 589,824 [post-attn, pre-h1sp]
  const size_t O_P2A  = 192675840;   // fc1 partials 2x2,408,448 [pre-h1sp]
  const size_t O_P2AB = O_P2A + 2408448;
  const size_t O_F1T  = 197492736;   // fc1T 2,359,296 [pre-h1sp]
  // fc2 phase (h1 region dead; yB live at 38.5..77MB):
  const size_t O_BT   = 0;           // bitsT 4,816,896
  const size_t O_F2T  = 4816896;     // fc2T 2,359,296
  const size_t O_P2B  = 77070336;    // fc2 partials 19,267,584
  const size_t O_P2BB = 96337920;    // fc2 partials^2 19,267,584

  float* xT    = (float*)(ws + O_XT);
  float* yQ    = (float*)(ws + O_YQ);
  float* yB    = (float*)(ws + O_YQ);
  float* h1    = (float*)(ws + O_H1);
  float* xres  = (float*)(ws + O_XRES);
  uint32_t* pkQKV = (uint32_t*)(ws + O_PK);
  uint8_t* spA   = (uint8_t*)(ws + O_SPA);
  uint8_t* h1sp  = (uint8_t*)(ws + O_H1SP);
  float* qkvT  = (float*)(ws + O_QKVT);
  float* projT = (float*)(ws + O_PRJT);
  float* fc1T  = (float*)(ws + O_F1T);
  float* fc2T  = (float*)(ws + O_F2T);
  uint32_t* bitsT = (uint32_t*)(ws + O_BT);
  double* p1S  = (double*)(ws + O_P1);
  double* p1S2 = (double*)(ws + O_P1B);
  double* p2aS  = (double*)(ws + O_P2A);
  double* p2aS2 = (double*)(ws + O_P2AB);
  double* p2bS  = (double*)(ws + O_P2B);
  double* p2bS2 = (double*)(ws + O_P2BB);
  float* mean_ = (float*)(ws + O_ST);
  float* rstd_ = (float*)(ws + O_ST + 6144);

  // 1. input transpose + qkv weight transpose (k-major, concatenated)
  k_transpose<<<dim3(CDIM * NBN / 256), 256, 0, stream>>>(x, xT);
  k_wT<<<dim3(12, 12), 256, 0, stream>>>(q_w, qkvT, 384, 1152, 0);
  k_wT<<<dim3(12, 12), 256, 0, stream>>>(k_w, qkvT, 384, 1152, 384);
  k_wT<<<dim3(12, 12), 256, 0, stream>>>(v_w, qkvT, 384, 1152, 768);

  // 2. fused q/k/v GEMM (chain-exact, 8x16 microtile) + BN partials + LIF
  k_gemmf<<<dim3(9, 98), 256, 0, stream>>>(
      qkvT, xT, (const float*)nullptr, yQ, p1S, p1S2, CDIM, 1152);
  k_bn_reduceN<<<dim3(1152), 64, 0, stream>>>(p1S, p1S2, mean_, rstd_, 1152, 98);
  k_lif_pack<<<dim3(1152), 256, 0, stream>>>(
      yQ, mean_, rstd_, q_gamma, k_gamma, v_gamma, q_beta, k_beta, v_beta, pkQKV);

  // 3. attention (exact integer popcount) -> u8 spikes
  k_attn_pop<<<dim3(BATCH * NHEAD), 256, 0, stream>>>(
      pkQKV, pkQKV + 393216, pkQKV + 786432, spA);

  // 4. proj GEMM (u8 B, MT=64, gy-fast) + BN + residual -> xres
  k_wT<<<dim3(12, 12), 256, 0, stream>>>(proj_w, projT, 384, 384, 0);
  k_gemmu8<<<dim3(6, 196), 256, 0, stream>>>(
      projT, spA, proj_b, yB, p1S, p1S2, CDIM, 384);
  k_bn_reduceN<<<dim3(384), 64, 0, stream>>>(p1S, p1S2, mean_, rstd_, 384, 196);
  k_bn_lif<1><<<dim3(9408), 256, 0, stream>>>(yB, mean_, rstd_, proj_gamma, proj_beta,
                                              xT, xres);

  // 5. fc1 GEMM (float B = xres, 8x16 microtile) -> u8 spikes
  k_wT<<<dim3(12, 48), 256, 0, stream>>>(fc1_w, fc1T, 384, 1536, 0);
  k_gemmf<<<dim3(12, 98), 256, 0, stream>>>(
      fc1T, xres, fc1_b, h1, p2aS, p2aS2, CDIM, 1536);
  k_bn_reduceN<<<dim3(1536), 64, 0, stream>>>(p2aS, p2aS2, mean_, rstd_, 1536, 98);
  k_lif_u8<<<dim3(1536), 256, 0, stream>>>(h1, mean_, rstd_,
                                           bn1_gamma, bn1_beta, h1sp);

  // 6. fc2 SPARSE-EXACT: repack bits -> bit-walk accumulate -> BN -> out
  k_wT<<<dim3(48, 12), 256, 0, stream>>>(fc2_w, fc2T, 1536, 384, 0);
  k_repack<<<dim3(NBN / 64), 256, 0, stream>>>(h1sp, bitsT);
  k_spgemm<<<dim3(NBN / 4), 256, 0, stream>>>(bitsT, fc2T, fc2_b, yB, p2bS, p2bS2);
  k_bn_reduceN<<<dim3(384), 64, 0, stream>>>(p2bS, p2bS2, mean_, rstd_, 384, NBN / 4);
  k_bn_lif<2><<<dim3(9408), 256, 0, stream>>>(yB, mean_, rstd_, bn2_gamma, bn2_beta,
                                              xres, out);
}

// Round 15
// 1035.424 us; speedup vs baseline: 1.0910x; 1.0910x over previous
//
#include <hip/hip_runtime.h>
#include <stdint.h>

#define NBN   25088   // 128 * 196  (TB * N)
#define NTOK  196
#define BATCH 32
#define CDIM  384
#define HDIM  1536
#define NHEAD 12

typedef float f32x4 __attribute__((ext_vector_type(4)));

#define GLDS16(g, l) __builtin_amdgcn_global_load_lds( \
    (const __attribute__((address_space(1))) void*)(g), \
    (__attribute__((address_space(3))) void*)(l), 16, 0, 0)

// ---------------- transpose: x (TB,C,N) -> xT (C, TB*N) ------------------------
__global__ __launch_bounds__(256) void k_transpose(const float* __restrict__ x,
                                                   float* __restrict__ xT) {
  int id = blockIdx.x * 256 + threadIdx.x;
  int c = id / NBN;
  int r = id - c * NBN;
  int b = r / NTOK;
  int n = r - b * NTOK;
  xT[id] = x[((size_t)b * CDIM + c) * NTOK + n];
}

// ---- weight transpose: src (R,C) -> dst[c*ldd + coff + r], grid (C/32, R/32) --
__global__ __launch_bounds__(256) void k_wT(const float* __restrict__ src,
                                            float* __restrict__ dst,
                                            int C, int ldd, int coff) {
  __shared__ float t[32][33];
  const int c0 = blockIdx.x * 32, r0 = blockIdx.y * 32;
  const int tx = threadIdx.x & 31, ty = threadIdx.x >> 5;   // 32 x 8
#pragma unroll
  for (int i = 0; i < 4; ++i)
    t[ty + i * 8][tx] = src[(size_t)(r0 + ty + i * 8) * C + c0 + tx];
  __syncthreads();
#pragma unroll
  for (int i = 0; i < 4; ++i)
    dst[(size_t)(c0 + ty + i * 8) * ldd + coff + r0 + tx] = t[tx][ty + i * 8];
}

// ---------------------------------------------------------------------------
// fp32 GEMM v10 (round-12-proven), chain-exact. BK=32, glds staging, one
// vmcnt(0)+barrier per tile, fragment register double-buffer. 1-D grid with
// BIJECTIVE XCD-CHUNKED SWIZZLE (m204): same-bn sibling blocks land in one
// XCD chunk -> B tile fetched once per XCD-L2. gy fast within chunk.
// MT = M-tile (128 float, 64 u8). Fused f64 BN partials.
// ---------------------------------------------------------------------------
template <typename TIN, int MT>
__global__ __launch_bounds__(256, 3) void k_gemm10(
    const float* __restrict__ WT, const TIN* __restrict__ X,
    const float* __restrict__ bias, float* __restrict__ Y,
    double* __restrict__ pS, double* __restrict__ pS2, int K, int Mtot, int ngy) {
  __shared__ float As[32][MT];
  __shared__ float Bs[32][128];
  constexpr int MR = MT / 16;
  const int tid = threadIdx.x;
  const int lane = tid & 63, wv = tid >> 6;
  // bijective XCD swizzle: hardware maps bid -> XCD bid%8 (heuristic only;
  // correctness independent of mapping since swizzle is bijective)
  const int nwg = gridDim.x;
  const int lid = blockIdx.x;
  const int xcd = lid & 7, pos = lid >> 3;
  const int q8 = nwg >> 3, rem = nwg & 7;
  const int wgid = (xcd < rem ? xcd * (q8 + 1)
                              : rem * (q8 + 1) + (xcd - rem) * q8) + pos;
  const int bn = wgid / ngy;
  const int gy = wgid - bn * ngy;
  const int wcol = gy * MT;
  const int tx = tid & 15, ty = tid >> 4;
  const int NK = K >> 5;

  float acc[MR][8];
#pragma unroll
  for (int i = 0; i < MR; ++i)
#pragma unroll
    for (int j = 0; j < 8; ++j) acc[i][j] = 0.f;

  for (int ks = 0; ks < NK; ++ks) {
    const int k0 = ks << 5;
    __syncthreads();
    if constexpr (MT == 128) {
      const int lrow = wv * 2 + (lane >> 5), lcol = (lane & 31) * 4;
#pragma unroll
      for (int i = 0; i < 4; ++i)
        GLDS16(WT + (size_t)(k0 + i * 8 + lrow) * Mtot + wcol + lcol,
               &As[i * 8 + wv * 2][0]);
    } else {
      const int lrow = wv * 4 + (lane >> 4), lcol = (lane & 15) * 4;
#pragma unroll
      for (int i = 0; i < 2; ++i)
        GLDS16(WT + (size_t)(k0 + i * 16 + lrow) * Mtot + wcol + lcol,
               &As[i * 16 + wv * 4][0]);
    }
    if constexpr (__is_same(TIN, float)) {
      const int lrow = wv * 2 + (lane >> 5), lcol = (lane & 31) * 4;
#pragma unroll
      for (int i = 0; i < 4; ++i)
        GLDS16(X + (size_t)(k0 + i * 8 + lrow) * NBN + bn * 128 + lcol,
               &Bs[i * 8 + wv * 2][0]);
    } else {
      const int r = tid >> 3, c16 = tid & 7;
      const uint4 d = *reinterpret_cast<const uint4*>(
          &X[(size_t)(k0 + r) * NBN + bn * 128 + c16 * 16]);
      const uint32_t wd[4] = {d.x, d.y, d.z, d.w};
#pragma unroll
      for (int q = 0; q < 4; ++q) {
        f32x4 f;
        f[0] = (float)(wd[q] & 0xffu);
        f[1] = (float)((wd[q] >> 8) & 0xffu);
        f[2] = (float)((wd[q] >> 16) & 0xffu);
        f[3] = (float)(wd[q] >> 24);
        *reinterpret_cast<f32x4*>(&Bs[r][c16 * 16 + q * 4]) = f;
      }
    }
    asm volatile("s_waitcnt vmcnt(0)" ::: "memory");
    __syncthreads();

    auto lA0 = [&](int kk) { return *reinterpret_cast<const f32x4*>(&As[kk][ty * 4]); };
    auto lA1 = [&](int kk) { return *reinterpret_cast<const f32x4*>(&As[kk][64 + ty * 4]); };
    auto lB0 = [&](int kk) { return *reinterpret_cast<const f32x4*>(&Bs[kk][tx * 4]); };
    auto lB1 = [&](int kk) { return *reinterpret_cast<const f32x4*>(&Bs[kk][64 + tx * 4]); };
    auto FMA = [&](f32x4 a0, f32x4 a1, f32x4 b0, f32x4 b1) {
#pragma unroll
      for (int i = 0; i < MR; ++i) {
        const float av = (i < 4) ? a0[i] : a1[i - 4];
#pragma unroll
        for (int j = 0; j < 8; ++j) {
          const float bv = (j < 4) ? b0[j] : b1[j - 4];
          acc[i][j] = fmaf(av, bv, acc[i][j]);
        }
      }
    };
    f32x4 xa0, xa1, xb0, xb1, ya0, ya1, yb0, yb1;
    xa0 = lA0(0);
    if constexpr (MT == 128) xa1 = lA1(0);
    xb0 = lB0(0);
    xb1 = lB1(0);
#pragma unroll
    for (int kk = 0; kk < 32; kk += 2) {
      ya0 = lA0(kk + 1);
      if constexpr (MT == 128) ya1 = lA1(kk + 1);
      yb0 = lB0(kk + 1);
      yb1 = lB1(kk + 1);
      FMA(xa0, xa1, xb0, xb1);
      if (kk + 2 < 32) {
        xa0 = lA0(kk + 2);
        if constexpr (MT == 128) xa1 = lA1(kk + 2);
        xb0 = lB0(kk + 2);
        xb1 = lB1(kk + 2);
      }
      FMA(ya0, ya1, yb0, yb1);
    }
  }

#pragma unroll
  for (int i = 0; i < MR; ++i) {
    const int rl = (MT == 128) ? ((i < 4) ? (ty * 4 + i) : (64 + ty * 4 + i - 4))
                               : (ty * 4 + i);
    const int row = wcol + rl;
    const float bv = bias ? bias[row] : 0.f;
    float4 o0, o1;
    o0.x = acc[i][0] + bv; o0.y = acc[i][1] + bv;
    o0.z = acc[i][2] + bv; o0.w = acc[i][3] + bv;
    o1.x = acc[i][4] + bv; o1.y = acc[i][5] + bv;
    o1.z = acc[i][6] + bv; o1.w = acc[i][7] + bv;
    *reinterpret_cast<float4*>(&Y[(size_t)row * NBN + bn * 128 + tx * 4]) = o0;
    *reinterpret_cast<float4*>(&Y[(size_t)row * NBN + bn * 128 + 64 + tx * 4]) = o1;
    double s = (double)o0.x + (double)o0.y + (double)o0.z + (double)o0.w +
               (double)o1.x + (double)o1.y + (double)o1.z + (double)o1.w;
    double s2 = (double)o0.x * o0.x + (double)o0.y * o0.y + (double)o0.z * o0.z +
                (double)o0.w * o0.w + (double)o1.x * o1.x + (double)o1.y * o1.y +
                (double)o1.z * o1.z + (double)o1.w * o1.w;
#pragma unroll
    for (int off = 1; off < 16; off <<= 1) {
      s += __shfl_xor(s, off, 64);
      s2 += __shfl_xor(s2, off, 64);
    }
    if (tx == 0) {
      pS[(size_t)bn * Mtot + row] = s;
      pS2[(size_t)bn * Mtot + row] = s2;
    }
  }
}

// ---- fused BN+LIF -> packed bits (fc1 output): one pass, no u8 intermediate --
// thread owns column r in [0,6272) and 32 channels of word w; chain t-ascending
// per (ch,col) identical to k_lif_u8 -> bit-exact decisions.
__global__ __launch_bounds__(128) void k_lif_bits(const float* __restrict__ Y,
    const float* __restrict__ mean, const float* __restrict__ rstd,
    const float* __restrict__ gamma, const float* __restrict__ beta,
    uint32_t* __restrict__ bitsT) {
  __shared__ float sm[32], sr[32], sg[32], sb[32];
  const int cb = blockIdx.x;   // 49 blocks over r
  const int w = blockIdx.y;    // 48 words
  const int tid = threadIdx.x;
  if (tid < 32) {
    const int ch = w * 32 + tid;
    sm[tid] = mean[ch]; sr[tid] = rstd[ch];
    sg[tid] = gamma[ch]; sb[tid] = beta[ch];
  }
  __syncthreads();
  const int r = cb * 128 + tid;
  float mem[32];
#pragma unroll
  for (int j = 0; j < 32; ++j) mem[j] = 0.f;
  for (int t = 0; t < 4; ++t) {
    uint32_t word = 0;
#pragma unroll
    for (int j = 0; j < 32; ++j) {
      const int ch = w * 32 + j;
      float v = Y[(size_t)ch * NBN + t * (BATCH * NTOK) + r];
      v = ((v - sm[j]) * sr[j]) * sg[j] + sb[j];
      float mm = mem[j];
      mm = mm + (v - mm) * 0.5f;
      bool fire = (mm >= 1.0f);
      mem[j] = fire ? 0.f : mm;
      word |= (fire ? 1u : 0u) << j;
    }
    bitsT[(size_t)(t * (BATCH * NTOK) + r) * 48 + w] = word;
  }
}

// ---- sparse-exact GEMM for fc2: y[row][c] = bias + sum_{k: s=1} wT[k][row] --
__global__ __launch_bounds__(256) void k_spgemm(
    const uint32_t* __restrict__ bitsT, const float* __restrict__ WT,
    const float* __restrict__ bias, float* __restrict__ Y,
    double* __restrict__ pS, double* __restrict__ pS2) {
  __shared__ float ytile[4][384];
  const int tid = threadIdx.x;
  const int lane = tid & 63, wv = tid >> 6;
  const int c = blockIdx.x * 4 + wv;
  const uint32_t* wb = bitsT + (size_t)c * 48;

  float a0 = 0.f, a1 = 0.f, a2 = 0.f, a3 = 0.f, a4 = 0.f, a5 = 0.f;
  for (int w = 0; w < 48; ++w) {
    uint32_t word = wb[w];
    while (word) {
      const int k = w * 32 + __builtin_ctz(word);
      word &= word - 1;
      const float* wr = WT + (size_t)k * 384;
      a0 += wr[lane];
      a1 += wr[64 + lane];
      a2 += wr[128 + lane];
      a3 += wr[192 + lane];
      a4 += wr[256 + lane];
      a5 += wr[320 + lane];
    }
  }
  ytile[wv][lane]       = a0 + bias[lane];
  ytile[wv][64 + lane]  = a1 + bias[64 + lane];
  ytile[wv][128 + lane] = a2 + bias[128 + lane];
  ytile[wv][192 + lane] = a3 + bias[192 + lane];
  ytile[wv][256 + lane] = a4 + bias[256 + lane];
  ytile[wv][320 + lane] = a5 + bias[320 + lane];
  __syncthreads();
  const int c0 = blockIdx.x * 4;
  for (int r = tid; r < 384; r += 256) {
    float4 v;
    v.x = ytile[0][r]; v.y = ytile[1][r]; v.z = ytile[2][r]; v.w = ytile[3][r];
    *reinterpret_cast<float4*>(&Y[(size_t)r * NBN + c0]) = v;
    double s = (double)v.x + (double)v.y + (double)v.z + (double)v.w;
    double s2 = (double)v.x * v.x + (double)v.y * v.y + (double)v.z * v.z +
                (double)v.w * v.w;
    pS[(size_t)blockIdx.x * 384 + r] = s;
    pS2[(size_t)blockIdx.x * 384 + r] = s2;
  }
}

// ---- BN stat reduce: NP f64 partials per channel ---------------------------
__global__ __launch_bounds__(64) void k_bn_reduceN(const double* __restrict__ pS,
                                                   const double* __restrict__ pS2,
                                                   float* __restrict__ mean,
                                                   float* __restrict__ rstd,
                                                   int Mtot, int NP) {
  const int ch = blockIdx.x, lane = threadIdx.x;
  double s = 0.0, s2 = 0.0;
  for (int j = lane; j < NP; j += 64) {
    s += pS[(size_t)j * Mtot + ch];
    s2 += pS2[(size_t)j * Mtot + ch];
  }
#pragma unroll
  for (int off = 32; off; off >>= 1) {
    s += __shfl_down(s, off, 64);
    s2 += __shfl_down(s2, off, 64);
  }
  if (lane == 0) {
    double m = s / (double)NBN;
    double v = s2 / (double)NBN - m * m;
    mean[ch] = (float)m;
    rstd[ch] = (float)(1.0 / sqrt(v + 1e-5));
  }
}

// ---- BN apply + LIF (thr 1.0) writing PACKED spikes (qkv -> attention) -----
__global__ __launch_bounds__(256) void k_lif_pack(const float* __restrict__ Y,
    const float* __restrict__ mean, const float* __restrict__ rstd,
    const float* __restrict__ g0, const float* __restrict__ g1,
    const float* __restrict__ g2, const float* __restrict__ b0,
    const float* __restrict__ b1, const float* __restrict__ b2,
    uint32_t* __restrict__ pk) {
  const int o = blockIdx.x;
  const int b = threadIdx.x >> 3, w = threadIdx.x & 7;
  int br = o / 384, ol = o - br * 384;
  const float g = (br == 0 ? g0 : br == 1 ? g1 : g2)[ol];
  const float be = (br == 0 ? b0 : br == 1 ? b1 : b2)[ol];
  const float m_ = mean[o], rs_ = rstd[o];
  float mem[32];
#pragma unroll
  for (int j = 0; j < 32; ++j) mem[j] = 0.f;
  for (int t = 0; t < 4; ++t) {
    uint32_t word = 0;
    const size_t base = (size_t)o * NBN + (size_t)(t * 32 + b) * NTOK + w * 32;
#pragma unroll
    for (int q = 0; q < 8; ++q) {
      if (w * 32 + q * 4 < NTOK) {
        float4 v4 = *reinterpret_cast<const float4*>(&Y[base + q * 4]);
        float vv[4] = {v4.x, v4.y, v4.z, v4.w};
#pragma unroll
        for (int jj = 0; jj < 4; ++jj) {
          int j = q * 4 + jj;
          float v = ((vv[jj] - m_) * rs_) * g + be;
          float mm = mem[j];
          mm = mm + (v - mm) * 0.5f;
          bool fire = (mm >= 1.0f);
          mem[j] = fire ? 0.f : mm;
          word |= (fire ? 1u : 0u) << j;
        }
      }
    }
    pk[((size_t)o * 128 + t * 32 + b) * 8 + w] = word;
  }
}

// ---- BN apply + LIF, float outputs -----------------------------------------
template <int MODE>
__global__ __launch_bounds__(256) void k_bn_lif(const float* __restrict__ Y,
                                                const float* __restrict__ mean,
                                                const float* __restrict__ rstd,
                                                const float* __restrict__ gamma,
                                                const float* __restrict__ beta,
                                                const float* __restrict__ addsrc,
                                                float* __restrict__ extra) {
  int id = blockIdx.x * 256 + threadIdx.x;
  int o = id / (BATCH * NTOK);
  int r = id - o * (BATCH * NTOK);
  float m_ = mean[o], rs_ = rstd[o], g = gamma[o], be = beta[o];
  float mem = 0.f;
#pragma unroll
  for (int t = 0; t < 4; ++t) {
    size_t idx = (size_t)o * NBN + (size_t)t * (BATCH * NTOK) + r;
    float v = Y[idx];
    v = ((v - m_) * rs_) * g + be;
    mem = mem + (v - mem) * 0.5f;
    bool fire = (mem >= 1.0f);
    float s = fire ? 1.f : 0.f;
    mem = fire ? 0.f : mem;
    if constexpr (MODE == 1) {
      extra[idx] = addsrc[idx] + s;
    } else {
      int b = r / NTOK, n = r - b * NTOK;
      extra[((size_t)(t * BATCH + b) * CDIM + o) * NTOK + n] = addsrc[idx] + s;
    }
  }
}

// ---- attention via popcount (exact integers), u8 output --------------------
__global__ __launch_bounds__(256) void k_attn_pop(const uint32_t* __restrict__ pQ,
                                                  const uint32_t* __restrict__ pK,
                                                  const uint32_t* __restrict__ pV,
                                                  uint8_t* __restrict__ spA) {
  __shared__ __align__(16) uint32_t qw[32][8], kw[32][8], vw[32][8];
  __shared__ int kv[32][33];
  __shared__ uint32_t kvb[8][32];
  __shared__ uint32_t qT[NTOK];
  const int bh = blockIdx.x;
  const int b_ = bh / NHEAD, h = bh - b_ * NHEAD;
  const int tid = threadIdx.x;
  const int e = tid >> 3, w = tid & 7;
  float mem[32];
#pragma unroll
  for (int j = 0; j < 32; ++j) mem[j] = 0.f;

  for (int t = 0; t < 4; ++t) {
    const int tb = t * 32 + b_;
    {
      int d = tid >> 3, wo = tid & 7;
      size_t base = ((size_t)(h * 32 + d) * 128 + tb) * 8 + wo;
      qw[d][wo] = pQ[base];
      kw[d][wo] = pK[base];
      vw[d][wo] = pV[base];
    }
    __syncthreads();
    for (int i = tid; i < 1024; i += 256) {
      int d = i >> 5, ee = i & 31;
      const uint64_t* kp = reinterpret_cast<const uint64_t*>(&kw[d][0]);
      const uint64_t* vp = reinterpret_cast<const uint64_t*>(&vw[ee][0]);
      int s = 0;
#pragma unroll
      for (int u = 0; u < 4; ++u) s += __popcll(kp[u] & vp[u]);
      kv[d][ee] = s;
    }
    __syncthreads();
    {
      int bitb = tid >> 5, ee = tid & 31;
      uint32_t mword = 0;
#pragma unroll
      for (int d = 0; d < 32; ++d) mword |= (uint32_t)((kv[d][ee] >> bitb) & 1) << d;
      kvb[bitb][ee] = mword;
    }
    if (tid < NTOK) {
      uint32_t mword = 0;
#pragma unroll
      for (int d = 0; d < 32; ++d)
        mword |= ((qw[d][tid >> 5] >> (tid & 31)) & 1u) << d;
      qT[tid] = mword;
    }
    __syncthreads();
    uint32_t word = 0;
#pragma unroll
    for (int j = 0; j < 32; ++j) {
      int n = w * 32 + j;
      if (n < NTOK) {
        uint32_t qm = qT[n];
        int acc = 0;
#pragma unroll
        for (int bb = 0; bb < 8; ++bb) acc += __popc(qm & kvb[bb][e]) << bb;
        float val = (float)acc * 0.125f;
        float mm = mem[j];
        mm = mm + (val - mm) * 0.5f;
        bool fire = (mm >= 0.5f);
        mem[j] = fire ? 0.f : mm;
        word |= (fire ? 1u : 0u) << j;
      }
    }
    uint8_t* dst = spA + (size_t)(h * 32 + e) * NBN + (size_t)tb * NTOK + w * 32;
#pragma unroll
    for (int q = 0; q < 8; ++q) {
      if (w * 32 + q * 4 < NTOK) {
        uint32_t b4 = ((word >> (q * 4)) & 1u) | (((word >> (q * 4 + 1)) & 1u) << 8) |
                      (((word >> (q * 4 + 2)) & 1u) << 16) |
                      (((word >> (q * 4 + 3)) & 1u) << 24);
        *reinterpret_cast<uint32_t*>(dst + q * 4) = b4;
      }
    }
    __syncthreads();
  }
}

// ---------------------------------------------------------------------------
extern "C" void kernel_launch(void* const* d_in, const int* in_sizes, int n_in,
                              void* d_out, int out_size, void* d_ws, size_t ws_size,
                              hipStream_t stream) {
  const float* x          = (const float*)d_in[0];
  const float* q_w        = (const float*)d_in[1];
  const float* q_gamma    = (const float*)d_in[2];
  const float* q_beta     = (const float*)d_in[3];
  const float* k_w        = (const float*)d_in[4];
  const float* k_gamma    = (const float*)d_in[5];
  const float* k_beta     = (const float*)d_in[6];
  const float* v_w        = (const float*)d_in[7];
  const float* v_gamma    = (const float*)d_in[8];
  const float* v_beta     = (const float*)d_in[9];
  const float* proj_w     = (const float*)d_in[10];
  const float* proj_b     = (const float*)d_in[11];
  const float* proj_gamma = (const float*)d_in[12];
  const float* proj_beta  = (const float*)d_in[13];
  const float* fc1_w      = (const float*)d_in[14];
  const float* fc1_b      = (const float*)d_in[15];
  const float* bn1_gamma  = (const float*)d_in[16];
  const float* bn1_beta   = (const float*)d_in[17];
  const float* fc2_w      = (const float*)d_in[18];
  const float* fc2_b      = (const float*)d_in[19];
  const float* bn2_gamma  = (const float*)d_in[20];
  const float* bn2_beta   = (const float*)d_in[21];
  float* out = (float*)d_out;
  char* ws = (char*)d_ws;

  // ---- arena (bytes); peak 231,223,296 = round-1-proven footprint --------
  const size_t O_XT   = 0;           // xT f32 (384,NBN) [1..proj-lif]
  const size_t O_YQ   = 38535168;    // yQKV (1152,NBN) / yB
  const size_t O_XRES = 154140672;   // xres (384,NBN) [proj-lif..end]
  const size_t O_PK   = 192675840;   // packed qkv bits 4,718,592
  const size_t O_SPA  = 197394432;   // attn u8 spikes 9,633,792
  const size_t O_H1   = 0;           // fc1 out f32 (1536,NBN)
  const size_t O_ST   = 231211008;   // mean/rstd
  // transient:
  const size_t O_P1   = 154140672;   // qkv/proj partials (consumed pre-xres)
  const size_t O_P1B  = O_P1 + 1806336;
  const size_t O_QKVT = 197394432;   // qkvT 1,769,472 [pre-attn]
  const size_t O_PRJT = 192675840;   // projT 589,824 [post-attn, pre-bitsT]
  const size_t O_P2A  = 192675840;   // fc1 partials 2x2,408,448 [pre-bitsT]
  const size_t O_P2AB = O_P2A + 2408448;
  const size_t O_F1T  = 197492736;   // fc1T 2,359,296 [pre-bitsT... dead by fc2]
  // fc2 phase:
  const size_t O_BT   = 192675840;   // bitsT 4,816,896 (h1sp region; h1 still live!)
  const size_t O_F2T  = 4816896;     // fc2T 2,359,296 (h1 region, h1 dead post-lif_bits)
  const size_t O_P2B  = 77070336;    // fc2 partials 19,267,584 (h1 dead)
  const size_t O_P2BB = 96337920;    // fc2 partials^2 19,267,584

  float* xT    = (float*)(ws + O_XT);
  float* yQ    = (float*)(ws + O_YQ);
  float* yB    = (float*)(ws + O_YQ);
  float* h1    = (float*)(ws + O_H1);
  float* xres  = (float*)(ws + O_XRES);
  uint32_t* pkQKV = (uint32_t*)(ws + O_PK);
  uint8_t* spA   = (uint8_t*)(ws + O_SPA);
  float* qkvT  = (float*)(ws + O_QKVT);
  float* projT = (float*)(ws + O_PRJT);
  float* fc1T  = (float*)(ws + O_F1T);
  float* fc2T  = (float*)(ws + O_F2T);
  uint32_t* bitsT = (uint32_t*)(ws + O_BT);
  double* p1S  = (double*)(ws + O_P1);
  double* p1S2 = (double*)(ws + O_P1B);
  double* p2aS  = (double*)(ws + O_P2A);
  double* p2aS2 = (double*)(ws + O_P2AB);
  double* p2bS  = (double*)(ws + O_P2B);
  double* p2bS2 = (double*)(ws + O_P2BB);
  float* mean_ = (float*)(ws + O_ST);
  float* rstd_ = (float*)(ws + O_ST + 6144);

  // 1. input transpose + qkv weight transpose (k-major, concatenated)
  k_transpose<<<dim3(CDIM * NBN / 256), 256, 0, stream>>>(x, xT);
  k_wT<<<dim3(12, 12), 256, 0, stream>>>(q_w, qkvT, 384, 1152, 0);
  k_wT<<<dim3(12, 12), 256, 0, stream>>>(k_w, qkvT, 384, 1152, 384);
  k_wT<<<dim3(12, 12), 256, 0, stream>>>(v_w, qkvT, 384, 1152, 768);

  // 2. fused q/k/v GEMM (chain-exact, XCD-swizzled) + BN partials + LIF
  k_gemm10<float, 128><<<dim3(9 * 196), 256, 0, stream>>>(
      qkvT, xT, (const float*)nullptr, yQ, p1S, p1S2, CDIM, 1152, 9);
  k_bn_reduceN<<<dim3(1152), 64, 0, stream>>>(p1S, p1S2, mean_, rstd_, 1152, 196);
  k_lif_pack<<<dim3(1152), 256, 0, stream>>>(
      yQ, mean_, rstd_, q_gamma, k_gamma, v_gamma, q_beta, k_beta, v_beta, pkQKV);

  // 3. attention (exact integer popcount) -> u8 spikes
  k_attn_pop<<<dim3(BATCH * NHEAD), 256, 0, stream>>>(
      pkQKV, pkQKV + 393216, pkQKV + 786432, spA);

  // 4. proj GEMM (u8 B, MT=64, XCD-swizzled) + BN + residual -> xres
  k_wT<<<dim3(12, 12), 256, 0, stream>>>(proj_w, projT, 384, 384, 0);
  k_gemm10<uint8_t, 64><<<dim3(6 * 196), 256, 0, stream>>>(
      projT, spA, proj_b, yB, p1S, p1S2, CDIM, 384, 6);
  k_bn_reduceN<<<dim3(384), 64, 0, stream>>>(p1S, p1S2, mean_, rstd_, 384, 196);
  k_bn_lif<1><<<dim3(9408), 256, 0, stream>>>(yB, mean_, rstd_, proj_gamma, proj_beta,
                                              xT, xres);

  // 5. fc1 GEMM (float B = xres, XCD-swizzled) -> fused BN+LIF+bitpack
  k_wT<<<dim3(12, 48), 256, 0, stream>>>(fc1_w, fc1T, 384, 1536, 0);
  k_gemm10<float, 128><<<dim3(12 * 196), 256, 0, stream>>>(
      fc1T, xres, fc1_b, h1, p2aS, p2aS2, CDIM, 1536, 12);
  k_bn_reduceN<<<dim3(1536), 64, 0, stream>>>(p2aS, p2aS2, mean_, rstd_, 1536, 196);
  k_lif_bits<<<dim3(49, 48), 128, 0, stream>>>(h1, mean_, rstd_,
                                               bn1_gamma, bn1_beta, bitsT);

  // 6. fc2 SPARSE-EXACT: bit-walk accumulate -> BN -> out
  k_wT<<<dim3(48, 12), 256, 0, stream>>>(fc2_w, fc2T, 1536, 384, 0);
  k_spgemm<<<dim3(NBN / 4), 256, 0, stream>>>(bitsT, fc2T, fc2_b, yB, p2bS, p2bS2);
  k_bn_reduceN<<<dim3(384), 64, 0, stream>>>(p2bS, p2bS2, mean_, rstd_, 384, NBN / 4);
  k_bn_lif<2><<<dim3(9408), 256, 0, stream>>>(yB, mean_, rstd_, bn2_gamma, bn2_beta,
                                              xres, out);
}